// Round 4
// baseline (411.657 us; speedup 1.0000x reference)
//
#include <hip/hip_runtime.h>
#include <hip/hip_bf16.h>

// TopKRouter: logits = x[16384,4096] @ W[64,4096]^T; softmax; top-2; z_loss.
// v5: FULLY FUSED gemm+softmax+top2 (KSPLIT=1, 256 blocks x 512 thr).
//  - v4 post-mortem: counted vmcnt was null because in-loop GLOBAL W-frag
//    loads poison the in-order vmcnt counter (waiting for b5 == drain all
//    older staging loads). Fix: stage W through the SAME global_load_lds
//    pipeline as x. K-loop body touches only LDS -> counted vmcnt is pure.
//  - panel = 64 K-floats: 16 KB x + 24 KB W frags, 3-deep buffers (120 KB
//    LDS), wait vmcnt(10) keeps ~2 panels in flight across barriers.
//  - 8 waves = 4 k-blocks x 2 row-halves; in-block 4-way K reduce in LDS;
//    softmax/top-2/z inline (no lg round-trip, no epilogue kernel).

typedef __bf16  bf16x8  __attribute__((ext_vector_type(8)));
typedef float   f32x16  __attribute__((ext_vector_type(16)));

#define BS_TOK 16384              // B*S tokens
#define H_DIM  4096
#define E_DIM  64
#define NPAN   64                 // panels of 64 floats covering K=4096
#define WS_ZBUF_OFF (1536u << 10) // z partials at +1.5 MiB (after 1.5 MiB wb)

// LDS float-offsets: 3 x-slots (16 KB each) then 3 W-slots (24 KB each)
#define XSLOT(s)  ((s) * 4096)
#define WSLOT(s)  (12288 + (s) * 6144)   // total 30720 floats = 120 KB

__device__ __forceinline__ void split3(float v, __bf16 &b0, __bf16 &b1, __bf16 &b2) {
    b0 = (__bf16)v;            // top 8 mantissa bits (RN)
    float r = v - (float)b0;   // exact in fp32
    b1 = (__bf16)r;            // next 8 bits
    float r2 = r - (float)b1;  // exact
    b2 = (__bf16)r2;           // v == b0+b1+b2 (within fp32)
}

__device__ __forceinline__ void async_copy16(const float* gp, float* lp) {
    __builtin_amdgcn_global_load_lds(
        (const __attribute__((address_space(1))) void*)gp,
        (__attribute__((address_space(3))) void*)lp, 16, 0, 0);
}

// Kernel 0: split gate_w into 3 bf16 terms in 32x32x16 MFMA B-frag order.
// frag f = (kb*2 + nt)*3 + term; element [f*64 + lane].
// lane holds W_term[n = nt*32 + (lane&31)][k = kb*16 + (lane>>5)*8 + j]
__global__ void prep_w(const float* __restrict__ gw, bf16x8* __restrict__ wb) {
    int idx  = blockIdx.x * blockDim.x + threadIdx.x;   // 0..32767
    int kb   = idx >> 7;
    int rem  = idx & 127;
    int nt   = rem >> 6;
    int lane = rem & 63;
    int n  = nt * 32 + (lane & 31);
    int kk = kb * 16 + ((lane >> 5) << 3);
    const float* p = gw + (size_t)n * H_DIM + kk;
    bf16x8 t0, t1, t2;
#pragma unroll
    for (int j = 0; j < 8; ++j) {
        __bf16 a, b, c;
        split3(p[j], a, b, c);
        t0[j] = a; t1[j] = b; t2[j] = c;
    }
    size_t fb = (size_t)(kb * 2 + nt) * 3;
    wb[(fb + 0) * 64 + lane] = t0;
    wb[(fb + 1) * 64 + lane] = t1;
    wb[(fb + 2) * 64 + lane] = t2;
}

// Kernel 1 (fused): block = 512 thr (8 waves), tile M64 x E64 x K4096.
// Wave w: k-block kb = w&3 of each panel, row-half rh = w>>2.
// Panel p staged to LDS slot p%3: x rows 0..63 x 64 floats (swizzled chunks)
// + the panel's 24 KB of W fragments (linear copy).
__global__ __launch_bounds__(512, 2) void fused(
        const float* __restrict__ x, const float* __restrict__ wbf,
        float* __restrict__ out, float* __restrict__ zbuf) {
    __shared__ float lds[30720];   // 120 KB: 3 x (16 KB x-panel + 24 KB W-panel)
    __shared__ float zsh[8];

    int bid = blockIdx.x;             // 0..255 (M64 tiles)
    int m0  = bid * 64;
    int tid = threadIdx.x;
    int w   = tid >> 6;               // wave 0..7
    int l   = tid & 63;
    int kb  = w & 3;                  // k-block within panel
    int rh  = w >> 2;                 // row-half

    int row  = rh * 32 + (l & 31);    // A row this wave/lane feeds
    int half = l >> 5;                // k sub-offset (lane>>5)*8
    int rsw  = row & 15;
    int c0   = kb * 4 + half * 2;     // first 16-B chunk of this lane's A frag

    // --- x staging (2 rounds of 16B per thread per panel, swizzled src) ---
    const float* gx[2]; int xo[2];
#pragma unroll
    for (int r = 0; r < 2; ++r) {
        int g = r * 32 + (tid >> 4);                // row in tile 0..63
        int c = (tid & 15) ^ (g & 15);              // swizzled global chunk
        gx[r] = x + (size_t)(m0 + g) * H_DIM + c * 4;
        xo[r] = r * 2048 + w * 256;                 // wave-uniform float offset
    }
    // --- W staging (3 rounds of 16B per thread per panel, linear) ---
    const float* gwp = wbf + tid * 4;               // + p*6144 + r*2048
    int wo = w * 256;                               // wave-uniform

    f32x16 acc0, acc1;
#pragma unroll
    for (int r = 0; r < 16; ++r) { acc0[r] = 0.f; acc1[r] = 0.f; }

    auto stage = [&](int p, int s) {
#pragma unroll
        for (int r = 0; r < 2; ++r)
            async_copy16(gx[r] + p * 64, &lds[XSLOT(s) + xo[r]]);
#pragma unroll
        for (int r = 0; r < 3; ++r)
            async_copy16(gwp + p * 6144 + r * 2048, &lds[WSLOT(s) + r * 2048 + wo]);
    };

    auto compute = [&](int p, int s) {
        const float* xb = &lds[XSLOT(s)];
        float4 xa = *(const float4*)&xb[row * 64 + ((c0 ^ rsw) << 2)];
        float4 xc = *(const float4*)&xb[row * 64 + (((c0 + 1) ^ rsw) << 2)];
        bf16x8 a0, a1, a2;
        float xs[8] = {xa.x, xa.y, xa.z, xa.w, xc.x, xc.y, xc.z, xc.w};
#pragma unroll
        for (int j = 0; j < 8; ++j) {
            __bf16 h0, h1, h2;
            split3(xs[j], h0, h1, h2);
            a0[j] = h0; a1[j] = h1; a2[j] = h2;
        }
        const bf16x8* wl = (const bf16x8*)&lds[WSLOT(s)];
        int fb = kb * 6 * 64 + l;
        bf16x8 b0 = wl[fb + 0*64], b1 = wl[fb + 1*64], b2 = wl[fb + 2*64];
        bf16x8 b3 = wl[fb + 3*64], b4 = wl[fb + 4*64], b5 = wl[fb + 5*64];
        // experts 0..31
        acc0 = __builtin_amdgcn_mfma_f32_32x32x16_bf16(a0, b0, acc0, 0, 0, 0);
        acc0 = __builtin_amdgcn_mfma_f32_32x32x16_bf16(a1, b0, acc0, 0, 0, 0);
        acc0 = __builtin_amdgcn_mfma_f32_32x32x16_bf16(a2, b0, acc0, 0, 0, 0);
        acc0 = __builtin_amdgcn_mfma_f32_32x32x16_bf16(a0, b1, acc0, 0, 0, 0);
        acc0 = __builtin_amdgcn_mfma_f32_32x32x16_bf16(a1, b1, acc0, 0, 0, 0);
        acc0 = __builtin_amdgcn_mfma_f32_32x32x16_bf16(a0, b2, acc0, 0, 0, 0);
        // experts 32..63
        acc1 = __builtin_amdgcn_mfma_f32_32x32x16_bf16(a0, b3, acc1, 0, 0, 0);
        acc1 = __builtin_amdgcn_mfma_f32_32x32x16_bf16(a1, b3, acc1, 0, 0, 0);
        acc1 = __builtin_amdgcn_mfma_f32_32x32x16_bf16(a2, b3, acc1, 0, 0, 0);
        acc1 = __builtin_amdgcn_mfma_f32_32x32x16_bf16(a0, b4, acc1, 0, 0, 0);
        acc1 = __builtin_amdgcn_mfma_f32_32x32x16_bf16(a1, b4, acc1, 0, 0, 0);
        acc1 = __builtin_amdgcn_mfma_f32_32x32x16_bf16(a0, b5, acc1, 0, 0, 0);
    };

    // prologue: 3 panels in flight (15 loads/thread outstanding)
    stage(0, 0); stage(1, 1); stage(2, 2);

    int sl = 0;
#pragma unroll 1
    for (int p = 0; p < 61; ++p) {
        // panel p's 5 loads landed; p+1, p+2 (10) stay in flight
        asm volatile("s_waitcnt vmcnt(10)" ::: "memory");
        __builtin_amdgcn_s_barrier();
        compute(p, sl);
        __builtin_amdgcn_s_barrier();   // all waves done reading slot sl
        stage(p + 3, sl);               // overwrite it with panel p+3
        sl = (sl == 2) ? 0 : sl + 1;
    }
    // peeled tail: p = 61, 62, 63 (slots 1, 2, 0)
    asm volatile("s_waitcnt vmcnt(10)" ::: "memory");
    __builtin_amdgcn_s_barrier();
    compute(61, 1);
    asm volatile("s_waitcnt vmcnt(5)" ::: "memory");
    __builtin_amdgcn_s_barrier();
    compute(62, 2);
    asm volatile("s_waitcnt vmcnt(0)" ::: "memory");
    __builtin_amdgcn_s_barrier();
    compute(63, 0);
    __syncthreads();

    // --- 4-way K-block reduction in LDS ---
    // C/D layout: col = lane&31, row = (reg&3) + 8*(reg>>2) + 4*(lane>>5)
    int col = l & 31;
    if (kb != 0) {   // k-blocks 1..3 deposit to scratch at 4096*kb
        float* b = &lds[kb * 4096];
#pragma unroll
        for (int r = 0; r < 16; ++r) {
            int mm = rh * 32 + (r & 3) + ((r >> 2) << 3) + (half << 2);
            b[mm * 64 + col]      = acc0[r];
            b[mm * 64 + 32 + col] = acc1[r];
        }
    }
    __syncthreads();
    if (kb == 0) {   // k-block 0 waves sum and write final logits to [0,4K)
#pragma unroll
        for (int r = 0; r < 16; ++r) {
            int mm = rh * 32 + (r & 3) + ((r >> 2) << 3) + (half << 2);
            int i0 = mm * 64 + col;
            lds[i0]      = acc0[r] + lds[4096 + i0] + lds[8192 + i0] + lds[12288 + i0];
            lds[i0 + 32] = acc1[r] + lds[4096 + i0 + 32] + lds[8192 + i0 + 32]
                                   + lds[12288 + i0 + 32];
        }
    }
    __syncthreads();

    // --- inline epilogue: each wave handles 8 tokens; lane = expert ---
    float zacc = 0.f;
#pragma unroll 1
    for (int i = 0; i < 8; ++i) {
        int tl = w * 8 + i;
        float lv = lds[tl * 64 + l];
        zacc += lv * lv;

        float m = lv;
#pragma unroll
        for (int off = 32; off; off >>= 1) m = fmaxf(m, __shfl_xor(m, off));
        float e = expf(lv - m);
        float d = e;
#pragma unroll
        for (int off = 32; off; off >>= 1) d += __shfl_xor(d, off);
        float sc = e / d;

        float s1 = sc; int i1 = l;
#pragma unroll
        for (int off = 32; off; off >>= 1) {
            float os = __shfl_xor(s1, off); int oi = __shfl_xor(i1, off);
            if (os > s1 || (os == s1 && oi < i1)) { s1 = os; i1 = oi; }
        }
        float sm = (l == i1) ? -1.0f : sc;
        float s2 = sm; int i2 = l;
#pragma unroll
        for (int off = 32; off; off >>= 1) {
            float os = __shfl_xor(s2, off); int oi = __shfl_xor(i2, off);
            if (os > s2 || (os == s2 && oi < i2)) { s2 = os; i2 = oi; }
        }
        if (l == 0) {
            int t = m0 + tl;
            out[2 * t]                  = (float)i1;
            out[2 * t + 1]              = (float)i2;
            out[2 * BS_TOK + 2 * t]     = s1;
            out[2 * BS_TOK + 2 * t + 1] = s2;
        }
    }
#pragma unroll
    for (int off = 32; off; off >>= 1) zacc += __shfl_xor(zacc, off);
    if (l == 0) zsh[w] = zacc;
    __syncthreads();
    if (tid == 0) {
        float s = 0.f;
#pragma unroll
        for (int i = 0; i < 8; ++i) s += zsh[i];
        zbuf[bid] = s;
    }
}

// Kernel 2: reduce 256 z partials -> aux_loss (=0) and z_loss.
__global__ __launch_bounds__(256) void zreduce(const float* __restrict__ zbuf,
                                               float* __restrict__ out) {
    __shared__ float sh[4];
    int tid = threadIdx.x;
    float s = zbuf[tid];
#pragma unroll
    for (int off = 32; off; off >>= 1) s += __shfl_xor(s, off);
    if ((tid & 63) == 0) sh[tid >> 6] = s;
    __syncthreads();
    if (tid == 0) {
        out[4 * BS_TOK]     = 0.0f;  // aux_loss
        out[4 * BS_TOK + 1] = (sh[0] + sh[1] + sh[2] + sh[3])
                              * (1.0f / (float)(BS_TOK * E_DIM));
    }
}

extern "C" void kernel_launch(void* const* d_in, const int* in_sizes, int n_in,
                              void* d_out, int out_size, void* d_ws, size_t ws_size,
                              hipStream_t stream) {
    const float* x  = (const float*)d_in[0];   // [4,4096,4096] f32
    const float* gw = (const float*)d_in[1];   // [64,4096] f32
    float* out  = (float*)d_out;               // idx | scores | aux | z
    bf16x8* wb  = (bf16x8*)d_ws;                           // 1.5 MiB W frags
    float*  zbf = (float*)((char*)d_ws + WS_ZBUF_OFF);     // 1 KiB z partials

    prep_w<<<128, 256, 0, stream>>>(gw, wb);
    fused<<<256, 512, 0, stream>>>(x, (const float*)wb, out, zbf);
    zreduce<<<1, 256, 0, stream>>>(zbf, out);
}